// Round 4
// baseline (942.710 us; speedup 1.0000x reference)
//
#include <hip/hip_runtime.h>

#define NT 256   // 4 waves; wave w owns gate-tiles 4w..4w+3 = units 16w..16w+15 (all 4 gates)

typedef _Float16 f16x8 __attribute__((ext_vector_type(8)));
typedef _Float16 f16x4 __attribute__((ext_vector_type(4)));
typedef float    f32x4 __attribute__((ext_vector_type(4)));

#define MFMA(a, b, c) __builtin_amdgcn_mfma_f32_16x16x32_f16((a), (b), (c), 0, 0, 0)

#if __has_builtin(__builtin_amdgcn_exp2f)
__device__ __forceinline__ float fexp(float x) { return __builtin_amdgcn_exp2f(x * 1.4426950408889634f); }
#else
__device__ __forceinline__ float fexp(float x) { return __expf(x); }
#endif
#if __has_builtin(__builtin_amdgcn_rcpf)
__device__ __forceinline__ float frcp(float x) { return __builtin_amdgcn_rcpf(x); }
#else
__device__ __forceinline__ float frcp(float x) { return 1.0f / x; }
#endif
__device__ __forceinline__ float sigm(float x)  { return frcp(1.0f + fexp(-x)); }
__device__ __forceinline__ float tanh_(float x) { return 1.0f - 2.0f * frcp(1.0f + fexp(2.0f * x)); }
__device__ __forceinline__ float lrelu(float x) { return x > 0.0f ? x : 0.01f * x; }

__device__ __forceinline__ f16x8 ld8(const float* p) {
    const float4* q = (const float4*)p;
    float4 a = q[0], b = q[1];
    f16x8 r = { (_Float16)a.x, (_Float16)a.y, (_Float16)a.z, (_Float16)a.w,
                (_Float16)b.x, (_Float16)b.y, (_Float16)b.z, (_Float16)b.w };
    return r;
}

__device__ __forceinline__ f16x8 zero8() {
    f16x8 z;
#pragma unroll
    for (int i = 0; i < 8; ++i) z[i] = (_Float16)0.0f;
    return z;
}

__global__ __launch_bounds__(NT, 1)
void gen_kernel(
    const float* __restrict__ noise,
    const float* __restrict__ w_ih0, const float* __restrict__ w_hh0,
    const float* __restrict__ b_ih0, const float* __restrict__ b_hh0,
    const float* __restrict__ w_ih1, const float* __restrict__ w_hh1,
    const float* __restrict__ b_ih1, const float* __restrict__ b_hh1,
    const float* __restrict__ w_ih2, const float* __restrict__ w_hh2,
    const float* __restrict__ b_ih2, const float* __restrict__ b_hh2,
    const float* __restrict__ fc1_w, const float* __restrict__ fc1_b,
    const float* __restrict__ fc2_w, const float* __restrict__ fc2_b,
    const float* __restrict__ fc3_w, const float* __restrict__ fc3_b,
    const int*   __restrict__ flow_len_p,
    float* __restrict__ out)
{
    // h-state, rotated banking: k-group kg of col c stored at slot (kg+c)&7.
    // Single-buffered; cross-step h1/h2 consumers carry data in registers.
    // Cols 8-15 are dead samples: zero-initialized and NEVER written (repack).
    __shared__ _Float16 sh[3][16 * 64] __attribute__((aligned(16)));   // 6 KB
    __shared__ _Float16 sy1[4][16][40] __attribute__((aligned(16)));   // per-wave head scratch
    __shared__ _Float16 sy2[4][16][40] __attribute__((aligned(16)));

    const int tid  = threadIdx.x;
    const int l    = tid & 63;
    const int w    = tid >> 6;     // wave 0..3
    const int ls   = l & 15;       // sample col (B/C) == row-in-tile (A)
    const int lj   = l >> 4;       // k-group / C row-group
    const int base = blockIdx.x * 8;
    const int T    = flow_len_p[0];

    // ---------- A fragments: 4 tiles per wave ----------
    f16x8 A1[4][4], A2[4][4], A0[4][3];
#pragma unroll
    for (int p = 0; p < 4; ++p) {
        const int rA = (ls & 3) * 64 + 4 * (4 * w + p) + (ls >> 2);
#pragma unroll
        for (int kc = 0; kc < 2; ++kc) {
            A1[p][kc]     = ld8(w_ih1 + rA * 64 + 32 * kc + 8 * lj);
            A1[p][2 + kc] = ld8(w_hh1 + rA * 64 + 32 * kc + 8 * lj);
            A2[p][kc]     = ld8(w_ih2 + rA * 64 + 32 * kc + 8 * lj);
            A2[p][2 + kc] = ld8(w_hh2 + rA * 64 + 32 * kc + 8 * lj);
            A0[p][kc]     = ld8(w_hh0 + rA * 64 + 32 * kc + 8 * lj);
        }
        f16x8 v;
#pragma unroll
        for (int i = 0; i < 8; ++i) {
            int kl = 8 * lj + i;
            float x = (kl < 3) ? w_ih0[rA * 3 + kl]
                    : (kl == 3) ? (b_ih0[rA] + b_hh0[rA]) : 0.0f;
            v[i] = (_Float16)x;
        }
        A0[p][2] = v;
    }
    // head A-frags (all 4 waves run the head redundantly)
    f16x8 F1[2][2], F2, F3;
#pragma unroll
    for (int tt = 0; tt < 2; ++tt)
#pragma unroll
        for (int kc = 0; kc < 2; ++kc)
            F1[tt][kc] = ld8(fc1_w + (16 * tt + ls) * 64 + 32 * kc + 8 * lj);
    F2 = ld8(fc2_w + ls * 32 + 8 * lj);
    {
        f16x8 v;
#pragma unroll
        for (int i = 0; i < 8; ++i) {
            int k = 8 * lj + i;
            v[i] = (_Float16)((ls < 3 && k < 16) ? fc3_w[ls * 16 + k] : 0.0f);
        }
        F3 = v;
    }
    // per-lane live cells after repack: units u0 (tiles p0/p1), u1 (tiles p2/p3), col cs
    const int u0 = 16 * w + ((ls < 8) ? 0 : 4) + lj;
    const int u1 = u0 + 8;
    const int cs = ls & 7;
    const int wh0 = cs * 64 + 8 * (((u0 >> 3) + cs) & 7) + (u0 & 7);
    const int wh1 = cs * 64 + 8 * (((u1 >> 3) + cs) & 7) + (u1 & 7);
    float b1o0[4], b1o1[4], b2o0[4], b2o1[4];
#pragma unroll
    for (int g = 0; g < 4; ++g) {
        b1o0[g] = b_ih1[g * 64 + u0] + b_hh1[g * 64 + u0];
        b1o1[g] = b_ih1[g * 64 + u1] + b_hh1[g * 64 + u1];
        b2o0[g] = b_ih2[g * 64 + u0] + b_hh2[g * 64 + u0];
        b2o1[g] = b_ih2[g * 64 + u1] + b_hh2[g * 64 + u1];
    }
    float hb1a[4], hb1b[4], hb2[4];
#pragma unroll
    for (int r = 0; r < 4; ++r) {
        hb1a[r] = fc1_b[4 * lj + r];
        hb1b[r] = fc1_b[16 + 4 * lj + r];
        hb2[r]  = fc2_b[4 * lj + r];
    }
    float fb3[3] = { fc3_b[0], fc3_b[1], fc3_b[2] };

    // ---------- LDS init ----------
    for (int i = tid; i < 3 * 16 * 64; i += NT) ((_Float16*)sh)[i] = (_Float16)0.0f;
    for (int i = tid; i < 4 * 16 * 40; i += NT) {
        ((_Float16*)sy1)[i] = (_Float16)0.0f;
        ((_Float16*)sy2)[i] = (_Float16)0.0f;   // k=16..31 stays 0 (zero-pad for by2)
    }
    __syncthreads();

    float c0a = 0.0f, c0b = 0.0f, c1a = 0.0f, c1b = 0.0f, c2a = 0.0f, c2b = 0.0f;
    const float zb[4] = {0, 0, 0, 0};

#define RD(L, kg) (*(const f16x8*)&sh[L][ls * 64 + 8 * (((kg) + ls) & 7)])

    // repack pair (even,odd) tiles: lane ls<8 keeps even's cell; ls>=8 takes partner's odd cell
#define REPACK(cell, a0, a1)                                                   \
    float cell[4];                                                             \
    _Pragma("unroll")                                                          \
    for (int r = 0; r < 4; ++r) {                                              \
        float v_ = __shfl_xor(a1[r], 8);                                       \
        cell[r] = (ls < 8) ? a0[r] : v_;                                       \
    }

#define ACTC(cell, bo, cref, L, wa) {                                          \
        float gi = cell[0] + bo[0], gf = cell[1] + bo[1];                      \
        float gg = cell[2] + bo[2], go = cell[3] + bo[3];                      \
        cref = sigm(gf) * cref + sigm(gi) * tanh_(gg);                         \
        sh[L][wa] = (_Float16)(sigm(go) * tanh_(cref)); }

    // ---------- prologue: h0(0) from noise (register-built B-frag) ----------
    {
        f16x8 bx0 = zero8();
        if (lj == 0) {
            float n0 = 0.0f, n1 = 0.0f, n2 = 0.0f;
            if (ls < 8) {
                const float* np = noise + (size_t)(base + ls) * 3;
                n0 = np[0]; n1 = np[1]; n2 = np[2];
            }
            bx0[0] = (_Float16)n0; bx0[1] = (_Float16)n1;
            bx0[2] = (_Float16)n2; bx0[3] = (_Float16)1.0f;
        }
        f32x4 g0 = {0,0,0,0}, g1 = {0,0,0,0}, g2 = {0,0,0,0}, g3 = {0,0,0,0};
        g0 = MFMA(A0[0][2], bx0, g0); g1 = MFMA(A0[1][2], bx0, g1);
        g2 = MFMA(A0[2][2], bx0, g2); g3 = MFMA(A0[3][2], bx0, g3);
        REPACK(cell0, g0, g1) ACTC(cell0, zb, c0a, 0, wh0)
        REPACK(cell1, g2, g3) ACTC(cell1, zb, c0b, 0, wh1)
    }
    // register-carried cross-step B-frags: h1(t-1), h2(t-1) = 0
    f16x8 h1r0 = zero8(), h1r1 = zero8();
    f16x8 h2r0 = zero8(), h2r1 = zero8();
    __syncthreads();

    // ---------- time loop: 3 barriers/step ----------
    for (int t = 0; t < T; ++t) {
        // I1: gates1 = [Wi1|Wh1]·[h0(t); h1(t-1)] -> h1(t)
        f16x8 r0 = RD(0, lj), r1 = RD(0, 4 + lj);
        {
            f32x4 g0 = {0,0,0,0}, g1 = {0,0,0,0}, g2 = {0,0,0,0}, g3 = {0,0,0,0};
            g0 = MFMA(A1[0][2], h1r0, g0); g1 = MFMA(A1[1][2], h1r0, g1);   // reg frags first
            g2 = MFMA(A1[2][2], h1r0, g2); g3 = MFMA(A1[3][2], h1r0, g3);
            g0 = MFMA(A1[0][3], h1r1, g0); g1 = MFMA(A1[1][3], h1r1, g1);
            g2 = MFMA(A1[2][3], h1r1, g2); g3 = MFMA(A1[3][3], h1r1, g3);
            g0 = MFMA(A1[0][0], r0, g0);   g1 = MFMA(A1[1][0], r0, g1);     // LDS-dep last
            g2 = MFMA(A1[2][0], r0, g2);   g3 = MFMA(A1[3][0], r0, g3);
            g0 = MFMA(A1[0][1], r1, g0);   g1 = MFMA(A1[1][1], r1, g1);
            g2 = MFMA(A1[2][1], r1, g2);   g3 = MFMA(A1[3][1], r1, g3);
            REPACK(cell0, g0, g1) ACTC(cell0, b1o0, c1a, 1, wh0)
            REPACK(cell1, g2, g3) ACTC(cell1, b1o1, c1b, 1, wh1)
        }
        __syncthreads();
        // I2: gates2 = [Wi2|Wh2]·[h1(t); h2(t-1)] -> h2(t)
        h1r0 = RD(1, lj); h1r1 = RD(1, 4 + lj);   // fresh h1(t); also next step's carry
        {
            f32x4 g0 = {0,0,0,0}, g1 = {0,0,0,0}, g2 = {0,0,0,0}, g3 = {0,0,0,0};
            g0 = MFMA(A2[0][2], h2r0, g0); g1 = MFMA(A2[1][2], h2r0, g1);
            g2 = MFMA(A2[2][2], h2r0, g2); g3 = MFMA(A2[3][2], h2r0, g3);
            g0 = MFMA(A2[0][3], h2r1, g0); g1 = MFMA(A2[1][3], h2r1, g1);
            g2 = MFMA(A2[2][3], h2r1, g2); g3 = MFMA(A2[3][3], h2r1, g3);
            g0 = MFMA(A2[0][0], h1r0, g0); g1 = MFMA(A2[1][0], h1r0, g1);
            g2 = MFMA(A2[2][0], h1r0, g2); g3 = MFMA(A2[3][0], h1r0, g3);
            g0 = MFMA(A2[0][1], h1r1, g0); g1 = MFMA(A2[1][1], h1r1, g1);
            g2 = MFMA(A2[2][1], h1r1, g2); g3 = MFMA(A2[3][1], h1r1, g3);
            REPACK(cell0, g0, g1) ACTC(cell0, b2o0, c2a, 2, wh0)
            REPACK(cell1, g2, g3) ACTC(cell1, b2o1, c2b, 2, wh1)
        }
        __syncthreads();
        // I3: head (all waves, per-wave LDS scratch) + layer0 update
        h2r0 = RD(2, lj); h2r1 = RD(2, 4 + lj);   // fresh h2(t); also next step's carry
        {
            f32x4 h0g0 = {0,0,0,0}, h0g1 = {0,0,0,0}, h0g2 = {0,0,0,0}, h0g3 = {0,0,0,0};
            h0g0 = MFMA(A0[0][0], r0, h0g0); h0g1 = MFMA(A0[1][0], r0, h0g1);  // Wh0 part, indep
            h0g2 = MFMA(A0[2][0], r0, h0g2); h0g3 = MFMA(A0[3][0], r0, h0g3);
            h0g0 = MFMA(A0[0][1], r1, h0g0); h0g1 = MFMA(A0[1][1], r1, h0g1);
            h0g2 = MFMA(A0[2][1], r1, h0g2); h0g3 = MFMA(A0[3][1], r1, h0g3);
            // y1 = fc1·h2 (rows 0-15 in y1a, 16-31 in y1b)
            f32x4 y1a = {0,0,0,0}, y1b = {0,0,0,0};
            y1a = MFMA(F1[0][0], h2r0, y1a); y1b = MFMA(F1[1][0], h2r0, y1b);
            y1a = MFMA(F1[0][1], h2r1, y1a); y1b = MFMA(F1[1][1], h2r1, y1b);
            f16x4 vv;
#pragma unroll
            for (int r = 0; r < 4; ++r) vv[r] = (_Float16)lrelu(y1a[r] + hb1a[r]);
            *(f16x4*)&sy1[w][ls][4 * lj] = vv;
#pragma unroll
            for (int r = 0; r < 4; ++r) vv[r] = (_Float16)lrelu(y1b[r] + hb1b[r]);
            *(f16x4*)&sy1[w][ls][16 + 4 * lj] = vv;
            f16x8 by1 = *(const f16x8*)&sy1[w][ls][8 * lj];
            f32x4 y2 = {0,0,0,0};
            y2 = MFMA(F2, by1, y2);
#pragma unroll
            for (int r = 0; r < 4; ++r) vv[r] = (_Float16)lrelu(y2[r] + hb2[r]);
            *(f16x4*)&sy2[w][ls][4 * lj] = vv;
            f16x8 by2 = *(const f16x8*)&sy2[w][ls][8 * lj];   // k>=16 reads zero-pad
            f32x4 y3 = {0,0,0,0};
            y3 = MFMA(F3, by2, y3);
            f16x8 bx = zero8();
            if (lj == 0) {
                float o0 = lrelu(y3[0] + fb3[0]);
                float o1 = lrelu(y3[1] + fb3[1]);
                float o2 = lrelu(y3[2] + fb3[2]);
                bx[0] = (_Float16)o0; bx[1] = (_Float16)o1;
                bx[2] = (_Float16)o2; bx[3] = (_Float16)1.0f;
                if (w == 0 && ls < 8) {
                    float* op = out + ((size_t)(base + ls) * T + t) * 3;
                    op[0] = o0; op[1] = o1; op[2] = o2;
                }
            }
            h0g0 = MFMA(A0[0][2], bx, h0g0); h0g1 = MFMA(A0[1][2], bx, h0g1);
            h0g2 = MFMA(A0[2][2], bx, h0g2); h0g3 = MFMA(A0[3][2], bx, h0g3);
            REPACK(cell0, h0g0, h0g1) ACTC(cell0, zb, c0a, 0, wh0)
            REPACK(cell1, h0g2, h0g3) ACTC(cell1, zb, c0b, 0, wh1)
        }
        __syncthreads();
    }
}

extern "C" void kernel_launch(void* const* d_in, const int* in_sizes, int n_in,
                              void* d_out, int out_size, void* d_ws, size_t ws_size,
                              hipStream_t stream) {
    const float* noise = (const float*)d_in[0];
    const float* w_ih0 = (const float*)d_in[1];
    const float* w_hh0 = (const float*)d_in[2];
    const float* b_ih0 = (const float*)d_in[3];
    const float* b_hh0 = (const float*)d_in[4];
    const float* w_ih1 = (const float*)d_in[5];
    const float* w_hh1 = (const float*)d_in[6];
    const float* b_ih1 = (const float*)d_in[7];
    const float* b_hh1 = (const float*)d_in[8];
    const float* w_ih2 = (const float*)d_in[9];
    const float* w_hh2 = (const float*)d_in[10];
    const float* b_ih2 = (const float*)d_in[11];
    const float* b_hh2 = (const float*)d_in[12];
    const float* fc1w  = (const float*)d_in[13];
    const float* fc1b  = (const float*)d_in[14];
    const float* fc2w  = (const float*)d_in[15];
    const float* fc2b  = (const float*)d_in[16];
    const float* fc3w  = (const float*)d_in[17];
    const float* fc3b  = (const float*)d_in[18];
    const int*   flp   = (const int*)d_in[19];

    gen_kernel<<<dim3(256), dim3(NT), 0, stream>>>(
        noise, w_ih0, w_hh0, b_ih0, b_hh0,
        w_ih1, w_hh1, b_ih1, b_hh1,
        w_ih2, w_hh2, b_ih2, b_hh2,
        fc1w, fc1b, fc2w, fc2b, fc3w, fc3b,
        flp, (float*)d_out);
}

// Round 5
// 805.938 us; speedup vs baseline: 1.1697x; 1.1697x over previous
//
#include <hip/hip_runtime.h>

#define NT 512   // 8 waves; wave w owns gate-tiles {2w,2w+1} = units 8w..8w+7 (all 4 gates)

typedef _Float16 f16x8 __attribute__((ext_vector_type(8)));
typedef _Float16 f16x4 __attribute__((ext_vector_type(4)));
typedef float    f32x4 __attribute__((ext_vector_type(4)));

#define MFMA(a, b, c) __builtin_amdgcn_mfma_f32_16x16x32_f16((a), (b), (c), 0, 0, 0)

#if __has_builtin(__builtin_amdgcn_exp2f)
__device__ __forceinline__ float fexp(float x) { return __builtin_amdgcn_exp2f(x * 1.4426950408889634f); }
#else
__device__ __forceinline__ float fexp(float x) { return __expf(x); }
#endif
#if __has_builtin(__builtin_amdgcn_rcpf)
__device__ __forceinline__ float frcp(float x) { return __builtin_amdgcn_rcpf(x); }
#else
__device__ __forceinline__ float frcp(float x) { return 1.0f / x; }
#endif
__device__ __forceinline__ float sigm(float x)  { return frcp(1.0f + fexp(-x)); }
__device__ __forceinline__ float tanh_(float x) { return 1.0f - 2.0f * frcp(1.0f + fexp(2.0f * x)); }
__device__ __forceinline__ float lrelu(float x) { return x > 0.0f ? x : 0.01f * x; }

__device__ __forceinline__ f16x8 ld8(const float* p) {
    const float4* q = (const float4*)p;
    float4 a = q[0], b = q[1];
    f16x8 r = { (_Float16)a.x, (_Float16)a.y, (_Float16)a.z, (_Float16)a.w,
                (_Float16)b.x, (_Float16)b.y, (_Float16)b.z, (_Float16)b.w };
    return r;
}

__global__ __launch_bounds__(NT, 2)
void gen_kernel(
    const float* __restrict__ noise,
    const float* __restrict__ w_ih0, const float* __restrict__ w_hh0,
    const float* __restrict__ b_ih0, const float* __restrict__ b_hh0,
    const float* __restrict__ w_ih1, const float* __restrict__ w_hh1,
    const float* __restrict__ b_ih1, const float* __restrict__ b_hh1,
    const float* __restrict__ w_ih2, const float* __restrict__ w_hh2,
    const float* __restrict__ b_ih2, const float* __restrict__ b_hh2,
    const float* __restrict__ fc1_w, const float* __restrict__ fc1_b,
    const float* __restrict__ fc2_w, const float* __restrict__ fc2_b,
    const float* __restrict__ fc3_w, const float* __restrict__ fc3_b,
    const int*   __restrict__ flow_len_p,
    float* __restrict__ out)
{
    // h-state, rotated banking (R11): k-group kg of col c stored at slot (kg+c)&7.
    // Cols 8-15 are dead samples: zero-initialized and NEVER written (repack).
    __shared__ _Float16 sh[3][2][16 * 64] __attribute__((aligned(16)));  // 12 KB
    __shared__ _Float16 sx [16][40] __attribute__((aligned(16)));
    __shared__ _Float16 sy1[16][40] __attribute__((aligned(16)));
    __shared__ _Float16 sy2[16][40] __attribute__((aligned(16)));
    // output ring: double-buffered 16-step chunks. Wave 0 writes (no global
    // stores on the critical wave!); wave 7 flushes the OTHER parity during
    // its idle window in I3 (hidden under wave 0's head).
    __shared__ float so[2][8][16][3] __attribute__((aligned(16)));       // 3 KB

    const int tid  = threadIdx.x;
    const int l    = tid & 63;
    const int w    = tid >> 6;     // wave 0..7
    const int ls   = l & 15;       // sample col (B/C) == row-in-tile (A)
    const int lj   = l >> 4;       // k-group / C row-group
    const int base = blockIdx.x * 8;
    const int T    = flow_len_p[0];

    // ---------- A fragments ----------
    const int gA  = ls & 3;
    const int rA0 = gA * 64 + 4 * (2 * w + 0) + (ls >> 2);
    const int rA1 = gA * 64 + 4 * (2 * w + 1) + (ls >> 2);

    f16x8 A1[2][4], A2[2][4], A0[2][3];
#pragma unroll
    for (int kc = 0; kc < 2; ++kc) {
        A1[0][kc]     = ld8(w_ih1 + rA0 * 64 + 32 * kc + 8 * lj);
        A1[1][kc]     = ld8(w_ih1 + rA1 * 64 + 32 * kc + 8 * lj);
        A1[0][2 + kc] = ld8(w_hh1 + rA0 * 64 + 32 * kc + 8 * lj);
        A1[1][2 + kc] = ld8(w_hh1 + rA1 * 64 + 32 * kc + 8 * lj);
        A2[0][kc]     = ld8(w_ih2 + rA0 * 64 + 32 * kc + 8 * lj);
        A2[1][kc]     = ld8(w_ih2 + rA1 * 64 + 32 * kc + 8 * lj);
        A2[0][2 + kc] = ld8(w_hh2 + rA0 * 64 + 32 * kc + 8 * lj);
        A2[1][2 + kc] = ld8(w_hh2 + rA1 * 64 + 32 * kc + 8 * lj);
        A0[0][kc]     = ld8(w_hh0 + rA0 * 64 + 32 * kc + 8 * lj);
        A0[1][kc]     = ld8(w_hh0 + rA1 * 64 + 32 * kc + 8 * lj);
    }
#pragma unroll
    for (int tt = 0; tt < 2; ++tt) {
        const int r = tt ? rA1 : rA0;
        f16x8 v;
#pragma unroll
        for (int i = 0; i < 8; ++i) {
            int kl = 8 * lj + i;
            float x = (kl < 3) ? w_ih0[r * 3 + kl]
                    : (kl == 3) ? (b_ih0[r] + b_hh0[r]) : 0.0f;
            v[i] = (_Float16)x;
        }
        A0[tt][2] = v;
    }
    // head A-frags (wave 0 uses them; cheap to load everywhere)
    f16x8 F1[2][2], F2, F3;
#pragma unroll
    for (int tt = 0; tt < 2; ++tt)
#pragma unroll
        for (int kc = 0; kc < 2; ++kc)
            F1[tt][kc] = ld8(fc1_w + (16 * tt + ls) * 64 + 32 * kc + 8 * lj);
    F2 = ld8(fc2_w + ls * 32 + 8 * lj);
    {
        f16x8 v;
#pragma unroll
        for (int i = 0; i < 8; ++i) {
            int k = 8 * lj + i;
            v[i] = (_Float16)((ls < 3 && k < 16) ? fc3_w[ls * 16 + k] : 0.0f);
        }
        F3 = v;
    }
    // per-lane live cell after repack: unit u_own, col cs
    const int uc0 = 8 * w + lj, uc1 = 8 * w + 4 + lj;
    const int u_own = (ls < 8) ? uc0 : uc1;
    const int cs    = ls & 7;
    const int whaddr = cs * 64 + 8 * (((u_own >> 3) + cs) & 7) + (u_own & 7);
    float b1o[4], b2o[4];
#pragma unroll
    for (int g = 0; g < 4; ++g) {
        b1o[g] = b_ih1[g * 64 + u_own] + b_hh1[g * 64 + u_own];
        b2o[g] = b_ih2[g * 64 + u_own] + b_hh2[g * 64 + u_own];
    }
    float hb1a[4], hb1b[4], hb2[4];
#pragma unroll
    for (int r = 0; r < 4; ++r) {
        hb1a[r] = fc1_b[4 * lj + r];
        hb1b[r] = fc1_b[16 + 4 * lj + r];
        hb2[r]  = fc2_b[4 * lj + r];
    }
    float fb3[3] = { fc3_b[0], fc3_b[1], fc3_b[2] };

    // ---------- LDS init ----------
    for (int i = tid; i < 3 * 2 * 16 * 64; i += NT) ((_Float16*)sh)[i] = (_Float16)0.0f;
    for (int i = tid; i < 16 * 40; i += NT) {
        ((_Float16*)sx)[i]  = (_Float16)0.0f;
        ((_Float16*)sy1)[i] = (_Float16)0.0f;
        ((_Float16*)sy2)[i] = (_Float16)0.0f;
    }
    __syncthreads();
    if (tid < 16) sx[tid][3] = (_Float16)1.0f;
    if (tid < 24) {
        int s = tid / 3, d = tid % 3;
        sx[s][d] = (_Float16)noise[(base + s) * 3 + d];
    }

    float c0s = 0.0f, c1s = 0.0f, c2s = 0.0f;
    const float zb[4] = {0, 0, 0, 0};
    __syncthreads();

#define RD(L, p, kg) (*(const f16x8*)&sh[L][p][ls * 64 + 8 * (((kg) + ls) & 7)])

    // repack: lane ls<8 keeps a0's cell; lane ls>=8 takes partner's a1 cell
#define REPACK(cell, a0, a1)                                                   \
    float cell[4];                                                             \
    _Pragma("unroll")                                                          \
    for (int r = 0; r < 4; ++r) {                                              \
        float v_ = __shfl_xor(a1[r], 8);                                       \
        cell[r] = (ls < 8) ? a0[r] : v_;                                       \
    }

#define ACTC(cell, bo, cref, L, p) {                                           \
        float gi = cell[0] + bo[0], gf = cell[1] + bo[1];                      \
        float gg = cell[2] + bo[2], go = cell[3] + bo[3];                      \
        cref = sigm(gf) * cref + sigm(gi) * tanh_(gg);                         \
        sh[L][p][whaddr] = (_Float16)(sigm(go) * tanh_(cref)); }

    // ---------- prologue: h0(0) from noise ----------
    {
        f16x8 bx = *(const f16x8*)&sx[ls][8 * lj];
        f32x4 a0 = {0, 0, 0, 0}, a1 = {0, 0, 0, 0};
        a0 = MFMA(A0[0][2], bx, a0);
        a1 = MFMA(A0[1][2], bx, a1);
        REPACK(cell, a0, a1)
        ACTC(cell, zb, c0s, 0, 0)
    }
    __syncthreads();
    // preload h1(buf1)=zeros for first I1
    f16x8 ph1a = RD(1, 1, lj), ph1b = RD(1, 1, 4 + lj);

    // ---------- time loop: 4 barriers/step ----------
    for (int t = 0; t < T; ++t) {
        const int pc = t & 1, pp = pc ^ 1;
        // I1: gates1 = [Wi1|Wh1]·[h0(pc); h1(pp)] -> ACT1 -> h1(pc)
        f16x8 r0 = RD(0, pc, lj), r1 = RD(0, pc, 4 + lj);
        f16x8 nh2a = RD(2, pp, lj), nh2b = RD(2, pp, 4 + lj);   // hoist for I2
        {
            f32x4 a0 = {0, 0, 0, 0}, a1 = {0, 0, 0, 0};
            a0 = MFMA(A1[0][0], r0, a0);   a1 = MFMA(A1[1][0], r0, a1);
            a0 = MFMA(A1[0][1], r1, a0);   a1 = MFMA(A1[1][1], r1, a1);
            a0 = MFMA(A1[0][2], ph1a, a0); a1 = MFMA(A1[1][2], ph1a, a1);
            a0 = MFMA(A1[0][3], ph1b, a0); a1 = MFMA(A1[1][3], ph1b, a1);
            REPACK(cell, a0, a1)
            ACTC(cell, b1o, c1s, 1, pc)
        }
        __syncthreads();
        // I2: gates2 = [Wi2|Wh2]·[h1(pc); h2(pp)] -> ACT2 -> h2(pc)
        {
            f16x8 s0 = RD(1, pc, lj), s1 = RD(1, pc, 4 + lj);
            f32x4 a0 = {0, 0, 0, 0}, a1 = {0, 0, 0, 0};
            a0 = MFMA(A2[0][0], s0, a0);   a1 = MFMA(A2[1][0], s0, a1);
            a0 = MFMA(A2[0][1], s1, a0);   a1 = MFMA(A2[1][1], s1, a1);
            a0 = MFMA(A2[0][2], nh2a, a0); a1 = MFMA(A2[1][2], nh2a, a1);
            a0 = MFMA(A2[0][3], nh2b, a0); a1 = MFMA(A2[1][3], nh2b, a1);
            REPACK(cell, a0, a1)
            ACTC(cell, b2o, c2s, 2, pc)
        }
        __syncthreads();
        // I3: layer0-hh from register-held r0,r1 (acc to I4)  ||  head on wave 0
        //     ||  output flush on wave 7 (hidden under wave 0's head)
        f32x4 h0a = {0, 0, 0, 0}, h0b = {0, 0, 0, 0};
        h0a = MFMA(A0[0][0], r0, h0a); h0b = MFMA(A0[1][0], r0, h0b);
        h0a = MFMA(A0[0][1], r1, h0a); h0b = MFMA(A0[1][1], r1, h0b);
        if (w == 0) {
            f16x8 bh0 = RD(2, pc, lj), bh1 = RD(2, pc, 4 + lj);
            f32x4 y1a = {0, 0, 0, 0}, y1b = {0, 0, 0, 0};
            y1a = MFMA(F1[0][0], bh0, y1a); y1b = MFMA(F1[1][0], bh0, y1b);
            y1a = MFMA(F1[0][1], bh1, y1a); y1b = MFMA(F1[1][1], bh1, y1b);
            f16x4 v;
#pragma unroll
            for (int r = 0; r < 4; ++r) v[r] = (_Float16)lrelu(y1a[r] + hb1a[r]);
            *(f16x4*)&sy1[ls][4 * lj] = v;
#pragma unroll
            for (int r = 0; r < 4; ++r) v[r] = (_Float16)lrelu(y1b[r] + hb1b[r]);
            *(f16x4*)&sy1[ls][16 + 4 * lj] = v;
            f16x8 by1 = *(const f16x8*)&sy1[ls][8 * lj];
            f32x4 y2 = {0, 0, 0, 0};
            y2 = MFMA(F2, by1, y2);
#pragma unroll
            for (int r = 0; r < 4; ++r) v[r] = (_Float16)lrelu(y2[r] + hb2[r]);
            *(f16x4*)&sy2[ls][4 * lj] = v;
            f16x8 by2 = *(const f16x8*)&sy2[ls][8 * lj];
            f32x4 y3 = {0, 0, 0, 0};
            y3 = MFMA(F3, by2, y3);
            if (lj == 0) {
                float o0 = lrelu(y3[0] + fb3[0]);
                float o1 = lrelu(y3[1] + fb3[1]);
                float o2 = lrelu(y3[2] + fb3[2]);
                sx[ls][0] = (_Float16)o0;
                sx[ls][1] = (_Float16)o1;
                sx[ls][2] = (_Float16)o2;
                if (ls < 8) {   // stash to LDS ring; NO global store on wave 0
                    float* sp = &so[(t >> 4) & 1][ls][t & 15][0];
                    sp[0] = o0; sp[1] = o1; sp[2] = o2;
                }
            }
        }
        if (w == 7 && t >= 16 && (t & 15) == 0) {
            // flush steps [t-16, t) from the other parity buffer.
            // All slots were written >= 2 barriers ago; wave 0 is writing the
            // opposite parity this chunk -> race-free.
            const int tb = t - 16, pb = (tb >> 4) & 1;
            for (int task = l; task < 96; task += 64) {         // 8 samples x 12 float4
                int s = task / 12, c = task % 12;
                *(float4*)(out + ((size_t)(base + s) * T + tb) * 3 + 4 * c) =
                    *(const float4*)((const float*)&so[pb][s][0][0] + 4 * c);
            }
        }
        __syncthreads();
        // I4: gates0 += Wi0p·[y3;1;0..] -> ACT0 -> h0(pp)
        {
            f16x8 bx = *(const f16x8*)&sx[ls][8 * lj];
            h0a = MFMA(A0[0][2], bx, h0a);
            h0b = MFMA(A0[1][2], bx, h0b);
            REPACK(cell, h0a, h0b)
            ACTC(cell, zb, c0s, 0, pp)
        }
        ph1a = RD(1, pc, lj); ph1b = RD(1, pc, 4 + lj);  // hoist for next I1
        __syncthreads();
    }

    // ---------- tail flush: steps [tf, T) ----------
    if (w == 7 && T > 0) {
        const int tf = ((T - 1) >> 4) << 4;
        const int pb = (tf >> 4) & 1;
        const int n  = T - tf;                 // 1..16
        for (int task = l; task < n * 8 * 3; task += 64) {
            int s = task / (n * 3), r = task % (n * 3);
            int q = r / 3, d = r % 3;
            out[((size_t)(base + s) * T + tf + q) * 3 + d] = so[pb][s][q][d];
        }
    }
}

extern "C" void kernel_launch(void* const* d_in, const int* in_sizes, int n_in,
                              void* d_out, int out_size, void* d_ws, size_t ws_size,
                              hipStream_t stream) {
    const float* noise = (const float*)d_in[0];
    const float* w_ih0 = (const float*)d_in[1];
    const float* w_hh0 = (const float*)d_in[2];
    const float* b_ih0 = (const float*)d_in[3];
    const float* b_hh0 = (const float*)d_in[4];
    const float* w_ih1 = (const float*)d_in[5];
    const float* w_hh1 = (const float*)d_in[6];
    const float* b_ih1 = (const float*)d_in[7];
    const float* b_hh1 = (const float*)d_in[8];
    const float* w_ih2 = (const float*)d_in[9];
    const float* w_hh2 = (const float*)d_in[10];
    const float* b_ih2 = (const float*)d_in[11];
    const float* b_hh2 = (const float*)d_in[12];
    const float* fc1w  = (const float*)d_in[13];
    const float* fc1b  = (const float*)d_in[14];
    const float* fc2w  = (const float*)d_in[15];
    const float* fc2b  = (const float*)d_in[16];
    const float* fc3w  = (const float*)d_in[17];
    const float* fc3b  = (const float*)d_in[18];
    const int*   flp   = (const int*)d_in[19];

    gen_kernel<<<dim3(256), dim3(NT), 0, stream>>>(
        noise, w_ih0, w_hh0, b_ih0, b_hh0,
        w_ih1, w_hh1, b_ih1, b_hh1,
        w_ih2, w_hh2, b_ih2, b_hh2,
        fc1w, fc1b, fc2w, fc2b, fc3w, fc3b,
        flp, (float*)d_out);
}